// Round 9
// baseline (393.899 us; speedup 1.0000x reference)
//
#include <hip/hip_runtime.h>
#include <hip/hip_bf16.h>
#include <hip/hip_cooperative_groups.h>
#include <stdint.h>

namespace cg = cooperative_groups;

#define NB 8192
#define ND 1024
#define NC 14

// rotl via single v_alignbit_b32: ((x:x) >> (32-r)) == rotl(x, r)
#define ROTL(x, r) __builtin_amdgcn_alignbit((x), (x), 32u - (r))
// single-instruction x1 = x1 + s + imm (imm in 1..5 = inline const)
#define ADD3_IMM(x, s, imm) \
  asm("v_add3_u32 %0, %1, %2, " #imm : "=v"(x) : "v"(x), "v"(s))

// ---------------- host Threefry-2x32 (20 rounds), JAX-compatible ----------------
static inline uint32_t rotl32h(uint32_t x, int r) { return (x << r) | (x >> (32 - r)); }
static void tf2x32_host(uint32_t k0, uint32_t k1, uint32_t x0, uint32_t x1,
                        uint32_t* o0, uint32_t* o1) {
  uint32_t ks[3] = { k0, k1, k0 ^ k1 ^ 0x1BD11BDAu };
  static const int R[8] = {13, 15, 26, 6, 17, 29, 16, 24};
  x0 += k0; x1 += k1;
  for (int g = 0; g < 5; ++g) {
    const int* rr = (g & 1) ? (R + 4) : R;
    for (int i = 0; i < 4; ++i) { x0 += x1; x1 = rotl32h(x1, rr[i]); x1 ^= x0; }
    x0 += ks[(g + 1) % 3];
    x1 += ks[(g + 2) % 3] + (uint32_t)(g + 1);
  }
  *o0 = x0; *o1 = x1;
}

// ---- per-row sampling + loss (identical math to R7's k_fused) ----
__device__ __forceinline__ void do_row(
    int i, uint32_t tid, const uint32_t* __restrict__ lbits2,
    const float* __restrict__ pred,
    uint32_t kp0, uint32_t kp1, uint32_t kps2,
    uint32_t kn0, uint32_t kn1, uint32_t kns2,
    float* __restrict__ losses) {
  const uint32_t bi = lbits2[i];
  const uint32_t ftP = kp1 + ((uint32_t)i << 13) + tid;  // K1 + fbase + tid
  const uint32_t ftN = kn1 + ((uint32_t)i << 13) + tid;

  // packed best: (key23 << 5) | (31-k) -> max == (max key, then min k = min j)
  uint32_t bkP = 0u, bkN = 0u;

#pragma unroll 8
  for (uint32_t k = 0; k < 32; ++k) {
    const uint32_t bj = lbits2[tid + (k << 8)];
    const uint32_t m = bi & bj;          // != 0  <=>  positive
    const uint32_t s0 = m ? kp0 : kn0;
    const uint32_t s1 = m ? kp1 : kn1;
    const uint32_t s2 = m ? kps2 : kns2;
    uint32_t x0 = s0;
    uint32_t x1 = (m ? ftP : ftN) + (k << 8);   // = K1 + (fbase + j)
#define TFR(r) { x0 += x1; x1 = ROTL(x1, r); x1 ^= x0; }
    TFR(13) TFR(15) TFR(26) TFR(6)
    x0 += s1;  ADD3_IMM(x1, s2, 1);
    TFR(17) TFR(29) TFR(16) TFR(24)
    x0 += s2;  ADD3_IMM(x1, s0, 2);
    TFR(13) TFR(15) TFR(26) TFR(6)
    x0 += s0;  ADD3_IMM(x1, s1, 3);
    TFR(17) TFR(29) TFR(16) TFR(24)
    x0 += s1;  ADD3_IMM(x1, s2, 4);
    TFR(13) TFR(15) TFR(26) TFR(6)
    x0 += s2;  ADD3_IMM(x1, s0, 5);
#undef TFR
    const uint32_t t = x0 ^ x1;
    const uint32_t cand = ((t >> 9) << 5) + (31u - k);
    const uint32_t selP = m ? cand : 0u;
    const uint32_t selN = cand ^ selP;            // m ? 0 : cand
    bkP = bkP > selP ? bkP : selP;                // v_max_u32
    bkN = bkN > selN ? bkN : selN;
  }

  // unpack to (key, j); reduce with (key desc, j asc) tie-break
  uint32_t keyP = bkP >> 5, jP = tid + ((31u - (bkP & 31u)) << 8);
  uint32_t keyN = bkN >> 5, jN = tid + ((31u - (bkN & 31u)) << 8);
#pragma unroll
  for (int off = 32; off > 0; off >>= 1) {
    uint32_t k2 = __shfl_down(keyP, off, 64), j2 = __shfl_down(jP, off, 64);
    if (k2 > keyP || (k2 == keyP && j2 < jP)) { keyP = k2; jP = j2; }
    k2 = __shfl_down(keyN, off, 64); j2 = __shfl_down(jN, off, 64);
    if (k2 > keyN || (k2 == keyN && j2 < jN)) { keyN = k2; jN = j2; }
  }
  __shared__ uint32_t sk[2][4], sj[2][4];
  __shared__ int spn[2];
  const int wave = (int)tid >> 6, lane = (int)tid & 63;
  if (lane == 0) { sk[0][wave] = keyP; sj[0][wave] = jP; sk[1][wave] = keyN; sj[1][wave] = jN; }
  __syncthreads();
  if (tid == 0) {
    uint32_t bk = sk[0][0], bj = sj[0][0];
#pragma unroll
    for (int w = 1; w < 4; ++w)
      if (sk[0][w] > bk || (sk[0][w] == bk && sj[0][w] < bj)) { bk = sk[0][w]; bj = sj[0][w]; }
    spn[0] = (int)bj;
    bk = sk[1][0]; bj = sj[1][0];
#pragma unroll
    for (int w = 1; w < 4; ++w)
      if (sk[1][w] > bk || (sk[1][w] == bk && sj[1][w] < bj)) { bk = sk[1][w]; bj = sj[1][w]; }
    spn[1] = (int)bj;
  }
  __syncthreads();

  // ---- fused loss for row i ----
  const int p = spn[0], n = spn[1];
  const float4* A  = (const float4*)(pred + (size_t)i * ND);
  const float4* P  = (const float4*)(pred + (size_t)p * ND);
  const float4* Nv = (const float4*)(pred + (size_t)n * ND);
  float4 a = A[tid], pv = P[tid], nv = Nv[tid];
  float na = a.x * a.x + a.y * a.y + a.z * a.z + a.w * a.w;
  float np = pv.x * pv.x + pv.y * pv.y + pv.z * pv.z + pv.w * pv.w;
  float nn = nv.x * nv.x + nv.y * nv.y + nv.z * nv.z + nv.w * nv.w;
  float dp = a.x * pv.x + a.y * pv.y + a.z * pv.z + a.w * pv.w;
  float dn = a.x * nv.x + a.y * nv.y + a.z * nv.z + a.w * nv.w;
#pragma unroll
  for (int o = 32; o > 0; o >>= 1) {
    na += __shfl_down(na, o, 64);
    np += __shfl_down(np, o, 64);
    nn += __shfl_down(nn, o, 64);
    dp += __shfl_down(dp, o, 64);
    dn += __shfl_down(dn, o, 64);
  }
  __shared__ float red[4][5];
  if (lane == 0) { red[wave][0] = na; red[wave][1] = np; red[wave][2] = nn;
                   red[wave][3] = dp; red[wave][4] = dn; }
  __syncthreads();
  if (tid == 0) {
    float NA = red[0][0] + red[1][0] + red[2][0] + red[3][0];
    float NP = red[0][1] + red[1][1] + red[2][1] + red[3][1];
    float NN = red[0][2] + red[1][2] + red[2][2] + red[3][2];
    float DP = red[0][3] + red[1][3] + red[2][3] + red[3][3];
    float DN = red[0][4] + red[1][4] + red[2][4] + red[3][4];
    NA = sqrtf(NA); NP = sqrtf(NP); NN = sqrtf(NN);
    float cp = DP / fmaxf(NA * NP, 1e-6f);
    float cn = DN / fmaxf(NA * NN, 1e-6f);
    losses[i] = fmaxf(cp - cn + 0.1f, 0.0f);
  }
  __syncthreads();   // protect shared arrays before next row reuses them
}

// ---------------- cooperative all-in-one (grid-stride, any grid size) ----------------
__global__ void __launch_bounds__(256) k_all(
    const float* __restrict__ gt, const float* __restrict__ pred,
    uint32_t* __restrict__ lbits2, float* __restrict__ losses,
    uint32_t kp0, uint32_t kp1, uint32_t kps2,
    uint32_t kn0, uint32_t kn1, uint32_t kns2,
    float* __restrict__ out) {
  cg::grid_group grid = cg::this_grid();
  const uint32_t tid = threadIdx.x;
  const int b = blockIdx.x;
  const int gsz = (int)gridDim.x;

  // ---- phase 1: label bitmasks, one row per thread, grid-stride ----
  for (int t = b * 256 + (int)tid; t < NB; t += gsz * 256) {
    uint32_t m = 0u;
#pragma unroll
    for (int c = 0; c < NC; ++c)
      m |= (gt[(size_t)t * NC + c] != 0.0f) ? (1u << c) : 0u;
    lbits2[t] = m ? m : 0x4000u;   // bit14 = unlabeled marker
  }
  grid.sync();

  // ---- phase 2: sampling + loss, grid-stride over rows ----
  for (int i = b; i < NB; i += gsz)
    do_row(i, tid, lbits2, pred, kp0, kp1, kps2, kn0, kn1, kns2, losses);
  grid.sync();

  // ---- phase 3: mean on block 0 ----
  if (b == 0) {
    float s = 0.0f;
    for (int k = (int)tid; k < NB; k += 256) s += losses[k];
#pragma unroll
    for (int o = 32; o > 0; o >>= 1) s += __shfl_down(s, o, 64);
    __shared__ float red2[4];
    const int wave = (int)tid >> 6, lane = (int)tid & 63;
    if (lane == 0) red2[wave] = s;
    __syncthreads();
    if (tid == 0) out[0] = (red2[0] + red2[1] + red2[2] + red2[3]) / (float)NB;
  }
}

// ---------------- fallback path (R7-proven 3-kernel pipeline) ----------------
__global__ void k_labels(const float* __restrict__ gt, uint32_t* __restrict__ lbits2) {
  const int i = blockIdx.x * 256 + threadIdx.x;
  uint32_t m = 0u;
#pragma unroll
  for (int c = 0; c < NC; ++c)
    m |= (gt[(size_t)i * NC + c] != 0.0f) ? (1u << c) : 0u;
  lbits2[i] = m ? m : 0x4000u;
}

__global__ void __launch_bounds__(256) k_fused(
    const uint32_t* __restrict__ lbits2, const float* __restrict__ pred,
    uint32_t kp0, uint32_t kp1, uint32_t kps2,
    uint32_t kn0, uint32_t kn1, uint32_t kns2,
    float* __restrict__ losses) {
  do_row(blockIdx.x, threadIdx.x, lbits2, pred, kp0, kp1, kps2, kn0, kn1, kns2, losses);
}

__global__ void k_mean(const float* __restrict__ losses, float* __restrict__ out) {
  float s = 0.0f;
  for (int k = threadIdx.x; k < NB; k += 256) s += losses[k];
#pragma unroll
  for (int o = 32; o > 0; o >>= 1) s += __shfl_down(s, o, 64);
  __shared__ float red[4];
  int wave = threadIdx.x >> 6, lane = threadIdx.x & 63;
  if (lane == 0) red[wave] = s;
  __syncthreads();
  if (threadIdx.x == 0) out[0] = (red[0] + red[1] + red[2] + red[3]) / (float)NB;
}

extern "C" void kernel_launch(void* const* d_in, const int* in_sizes, int n_in,
                              void* d_out, int out_size, void* d_ws, size_t ws_size,
                              hipStream_t stream) {
  const float* pred = (const float*)d_in[0]; // [8192,1024] f32
  const float* gt   = (const float*)d_in[1]; // [8192,14]  f32
  float* out = (float*)d_out;

  char* ws = (char*)d_ws;
  uint32_t* lbits  = (uint32_t*)(ws);        // 32 KiB
  float*    losses = (float*)(ws + 32768);   // 32 KiB

  // JAX partitionable-threefry: key(42) = (0,42); split -> kp=T(key,(0,0)), kn=T(key,(0,1))
  uint32_t kp0, kp1, kn0, kn1;
  tf2x32_host(0u, 42u, 0u, 0u, &kp0, &kp1);
  tf2x32_host(0u, 42u, 0u, 1u, &kn0, &kn1);
  uint32_t kps2 = kp0 ^ kp1 ^ 0x1BD11BDAu;
  uint32_t kns2 = kn0 ^ kn1 ^ 0x1BD11BDAu;

  // Size the cooperative grid from actual occupancy (host query, capture-safe,
  // deterministic). R8 lesson: hardcoding the max (8 blocks/CU) fails launch.
  int bpc = 0;
  hipError_t qe = hipOccupancyMaxActiveBlocksPerMultiprocessor(&bpc, (const void*)k_all, 256, 0);
  hipError_t le = hipErrorUnknown;
  if (qe == hipSuccess && bpc > 0) {
    int grid = bpc * 256;               // 256 CUs
    if (grid > 2048) grid = 2048;       // no benefit past 8/CU
    void* args[] = { (void*)&gt, (void*)&pred, (void*)&lbits, (void*)&losses,
                     (void*)&kp0, (void*)&kp1, (void*)&kps2,
                     (void*)&kn0, (void*)&kn1, (void*)&kns2, (void*)&out };
    le = hipLaunchCooperativeKernel((const void*)k_all, dim3(grid), dim3(256),
                                    args, 0, stream);
  }
  if (le != hipSuccess) {
    // R7-proven fallback (identical math)
    k_labels<<<NB / 256, 256, 0, stream>>>(gt, lbits);
    k_fused<<<NB, 256, 0, stream>>>(lbits, pred, kp0, kp1, kps2, kn0, kn1, kns2, losses);
    k_mean<<<1, 256, 0, stream>>>(losses, out);
  }
}